// Round 2
// baseline (232.688 us; speedup 1.0000x reference)
//
#include <hip/hip_runtime.h>
#include <math.h>

#define B 32
#define K 4
#define C 256
#define HW 1024          // H*W = 32*32
#define NT 5             // K+1 tensors (y, x0..x3)
#define MID 32
#define FEAT 1280        // NT*C
#define EPS 1e-5f

// ---------------------------------------------------------------------------
// Kernel 1: spatial mean per (tensor, b, c).  One wave (64 lanes) per
// reduction of HW=1024 floats.  4 waves / 256-thread block.
// feats layout: [B][FEAT] with slot t*C+c  (t=0 is y, t=1..4 are x0..x3).
// ---------------------------------------------------------------------------
__global__ __launch_bounds__(256) void mean_kernel(
    const float* __restrict__ y,
    const float* __restrict__ x0, const float* __restrict__ x1,
    const float* __restrict__ x2, const float* __restrict__ x3,
    float* __restrict__ feats)
{
    int wave = (blockIdx.x << 2) + (threadIdx.x >> 6);
    int lane = threadIdx.x & 63;
    // wave in [0, NT*B*C)
    int t   = wave / (B * C);
    int rem = wave - t * (B * C);
    int b   = rem >> 8;      // / C
    int c   = rem & 255;     // % C
    const float* src = (t == 0) ? y : (t == 1) ? x0 : (t == 2) ? x1
                                    : (t == 3) ? x2 : x3;
    const float4* p = (const float4*)(src + (size_t)(b * C + c) * HW);
    // 4 fully-coalesced float4 loads per lane: lane i, pass j reads bytes
    // j*1024 + i*16  -> each instruction covers a contiguous 1 KiB.
    float4 v0 = p[lane];
    float4 v1 = p[lane + 64];
    float4 v2 = p[lane + 128];
    float4 v3 = p[lane + 192];
    float s = v0.x + v0.y + v0.z + v0.w
            + v1.x + v1.y + v1.z + v1.w
            + v2.x + v2.y + v2.z + v2.w
            + v3.x + v3.y + v3.z + v3.w;
#pragma unroll
    for (int m = 32; m >= 1; m >>= 1) s += __shfl_xor(s, m);
    if (lane == 0) feats[b * FEAT + t * C + c] = s * (1.0f / 1024.0f);
}

// ---------------------------------------------------------------------------
// Kernel 2: gate MLP.  One block per batch element.
//   h = ReLU(BN(feats @ conv1_w^T))          [MID]
//   w = h @ conv2_w^T + conv2_b              [FEAT] = [5][C]
//   gates[b][0][c]   = sigmoid(w[0][c])
//   gates[b][1+k][c] = softmax_k(w[1+k][c])
// ---------------------------------------------------------------------------
__global__ __launch_bounds__(256) void gate_kernel(
    const float* __restrict__ feats,
    const float* __restrict__ conv1_w,   // [MID][FEAT]
    const float* __restrict__ bn_gamma, const float* __restrict__ bn_beta,
    const float* __restrict__ bn_mean,  const float* __restrict__ bn_var,
    const float* __restrict__ conv2_w,   // [FEAT][MID]
    const float* __restrict__ conv2_b,   // [FEAT]
    float* __restrict__ gates)           // [B][NT][C]
{
    __shared__ float feats_s[FEAT];
    __shared__ float partial[256];
    __shared__ float h_s[MID];

    const int b   = blockIdx.x;
    const int tid = threadIdx.x;

#pragma unroll
    for (int r = 0; r < 5; ++r)
        feats_s[tid + r * 256] = feats[b * FEAT + tid + r * 256];
    __syncthreads();

    // GEMM1: 256 threads = 32 m-values x 8 j-groups of 160 elements.
    const int m = tid & 31;
    const int g = tid >> 5;
    const float4* wrow = (const float4*)(conv1_w + m * FEAT + g * 160);
    float acc = 0.f;
#pragma unroll
    for (int i = 0; i < 40; ++i) {
        float4 wv = wrow[i];
        int j = g * 160 + i * 4;
        acc += wv.x * feats_s[j]     + wv.y * feats_s[j + 1]
             + wv.z * feats_s[j + 2] + wv.w * feats_s[j + 3];
    }
    partial[tid] = acc;
    __syncthreads();
    if (tid < 128) partial[tid] += partial[tid + 128];
    __syncthreads();
    if (tid < 64)  partial[tid] += partial[tid + 64];
    __syncthreads();
    if (tid < 32) {
        float hv  = partial[tid] + partial[tid + 32];
        float inv = rsqrtf(bn_var[tid] + EPS);
        hv = (hv - bn_mean[tid]) * (bn_gamma[tid] * inv) + bn_beta[tid];
        h_s[tid] = fmaxf(hv, 0.f);
    }
    __syncthreads();

    // GEMM2 + gate nonlinearities: thread tid == channel c, computes all 5
    // slots {w[r][c]} in registers.
    float wv[5];
#pragma unroll
    for (int r = 0; r < 5; ++r) {
        const int j = r * 256 + tid;
        const float4* w2 = (const float4*)(conv2_w + j * MID);
        float a = conv2_b[j];
#pragma unroll
        for (int i = 0; i < 8; ++i) {
            float4 q = w2[i];
            a += q.x * h_s[i * 4]     + q.y * h_s[i * 4 + 1]
               + q.z * h_s[i * 4 + 2] + q.w * h_s[i * 4 + 3];
        }
        wv[r] = a;
    }
    const float w1 = 1.f / (1.f + expf(-wv[0]));
    const float mx = fmaxf(fmaxf(wv[1], wv[2]), fmaxf(wv[3], wv[4]));
    const float e1 = expf(wv[1] - mx), e2 = expf(wv[2] - mx);
    const float e3 = expf(wv[3] - mx), e4 = expf(wv[4] - mx);
    const float inv = 1.f / (e1 + e2 + e3 + e4);
    gates[b * FEAT +        tid] = w1;
    gates[b * FEAT +  256 + tid] = e1 * inv;
    gates[b * FEAT +  512 + tid] = e2 * inv;
    gates[b * FEAT +  768 + tid] = e3 * inv;
    gates[b * FEAT + 1024 + tid] = e4 * inv;
}

// ---------------------------------------------------------------------------
// Kernel 3: out[b,c,:,:] = g0*y + g1*x0 + g2*x1 + g3*x2 + g4*x3.
// One block per (b,c) slice: 256 threads x float4 = 1024 floats.
// Gate loads are wave-uniform (scalar).
// ---------------------------------------------------------------------------
__global__ __launch_bounds__(256) void out_kernel(
    const float* __restrict__ y,
    const float* __restrict__ x0, const float* __restrict__ x1,
    const float* __restrict__ x2, const float* __restrict__ x3,
    const float* __restrict__ gates,
    float* __restrict__ out)
{
    const int bc = blockIdx.x;
    const int b  = bc >> 8;
    const int c  = bc & 255;
    const float g0 = gates[b * FEAT +        c];
    const float g1 = gates[b * FEAT +  256 + c];
    const float g2 = gates[b * FEAT +  512 + c];
    const float g3 = gates[b * FEAT +  768 + c];
    const float g4 = gates[b * FEAT + 1024 + c];

    const size_t base = (size_t)bc * HW;
    const int i = threadIdx.x;
    float4 vy = ((const float4*)(y  + base))[i];
    float4 v0 = ((const float4*)(x0 + base))[i];
    float4 v1 = ((const float4*)(x1 + base))[i];
    float4 v2 = ((const float4*)(x2 + base))[i];
    float4 v3 = ((const float4*)(x3 + base))[i];
    float4 r;
    r.x = vy.x * g0 + v0.x * g1 + v1.x * g2 + v2.x * g3 + v3.x * g4;
    r.y = vy.y * g0 + v0.y * g1 + v1.y * g2 + v2.y * g3 + v3.y * g4;
    r.z = vy.z * g0 + v0.z * g1 + v1.z * g2 + v2.z * g3 + v3.z * g4;
    r.w = vy.w * g0 + v0.w * g1 + v1.w * g2 + v2.w * g3 + v3.w * g4;
    ((float4*)(out + base))[i] = r;
}

// ---------------------------------------------------------------------------
extern "C" void kernel_launch(void* const* d_in, const int* in_sizes, int n_in,
                              void* d_out, int out_size, void* d_ws, size_t ws_size,
                              hipStream_t stream) {
    const float* y        = (const float*)d_in[0];
    const float* x0       = (const float*)d_in[1];
    const float* x1       = (const float*)d_in[2];
    const float* x2       = (const float*)d_in[3];
    const float* x3       = (const float*)d_in[4];
    const float* conv1_w  = (const float*)d_in[5];
    const float* bn_gamma = (const float*)d_in[6];
    const float* bn_beta  = (const float*)d_in[7];
    const float* bn_mean  = (const float*)d_in[8];
    const float* bn_var   = (const float*)d_in[9];
    const float* conv2_w  = (const float*)d_in[10];
    const float* conv2_b  = (const float*)d_in[11];

    float* feats = (float*)d_ws;             // [B][FEAT]
    float* gates = feats + B * FEAT;         // [B][NT][C]
    float* out   = (float*)d_out;

    // 1) means: NT*B*C = 40960 waves, 4 waves/block -> 10240 blocks
    mean_kernel<<<(NT * B * C) / 4, 256, 0, stream>>>(y, x0, x1, x2, x3, feats);
    // 2) gate MLP: one block per batch element
    gate_kernel<<<B, 256, 0, stream>>>(feats, conv1_w, bn_gamma, bn_beta,
                                       bn_mean, bn_var, conv2_w, conv2_b, gates);
    // 3) gated sum: one block per (b,c)
    out_kernel<<<B * C, 256, 0, stream>>>(y, x0, x1, x2, x3, gates, out);
}